// Round 1
// baseline (2010.811 us; speedup 1.0000x reference)
//
#include <hip/hip_runtime.h>
#include <math.h>

// NeuralSplineCoupling: y[:, :3] = RQS(x[:, :3]; params = MLP([x[:,3:], c]))
//                       y[:, 3:] = x[:, 3:],  log_det = sum over 3 dims
// N = 500000, X_DIM=6, C_DIM=4, HID=128, KNOTS=16, SPLINE_DIM=47, OUT_DIM=141

#define TILE 32      // samples per block; 500000 = 32 * 15625 exactly
#define NT 256
#define HID 128
#define OUTD 141
#define AS 132       // LDS row stride for h1/h2 (132 % 4 == 0 -> 16B aligned rows; 132*4 mod 128B spreads banks)
#define PS 145       // LDS row stride for p
#define BND 5.0f

__global__ __launch_bounds__(NT) void nsc_fused_kernel(
    const float* __restrict__ x, const float* __restrict__ c,
    const float* __restrict__ W1, const float* __restrict__ b1,
    const float* __restrict__ W2, const float* __restrict__ b2,
    const float* __restrict__ W3, const float* __restrict__ b3,
    float* __restrict__ out_y, float* __restrict__ out_ld, int N)
{
    __shared__ float sh_h[TILE * 8];     // input features [upper(3), c(4)], padded to 8
    __shared__ float sh1[TILE * AS];     // h1
    __shared__ float sh2[TILE * AS];     // h2
    __shared__ float shp[TILE * PS];     // p (141 cols)
    __shared__ float shld[TILE * 3];     // per-dim log-det

    const int tid = threadIdx.x;
    const int g0 = blockIdx.x * TILE;

    // ---- Phase 0: stage h = [x_upper(3), c(4)] ----
    if (tid < TILE * 7) {
        int s = tid / 7, k = tid - s * 7;
        int g = g0 + s;
        float v = 0.f;
        if (g < N) v = (k < 3) ? x[g * 6 + 3 + k] : c[g * 4 + (k - 3)];
        sh_h[s * 8 + k] = v;
    }
    __syncthreads();

    // ---- Phase 1: h1 = relu(h @ W1 + b1)   (7 -> 128) ----
    {
        const int j = tid & 127;
        const int sb = tid >> 7;             // 0 or 1
        float bj = b1[j];
        float w[7];
        #pragma unroll
        for (int k = 0; k < 7; ++k) w[k] = W1[k * HID + j];
        #pragma unroll
        for (int i = 0; i < TILE / 2; ++i) {
            int s = sb + 2 * i;
            float acc = bj;
            #pragma unroll
            for (int k = 0; k < 7; ++k) acc += sh_h[s * 8 + k] * w[k];
            sh1[s * AS + j] = fmaxf(acc, 0.f);
        }
    }
    __syncthreads();

    // ---- Phase 2: h2 = relu(h1 @ W2 + b2)  (128 -> 128), 2 samples x 8 cols per thread ----
    {
        const int jt = tid & 15, st = tid >> 4;
        const int j0 = jt * 8, s0 = st * 2;
        float acc0[8], acc1[8];
        #pragma unroll
        for (int q = 0; q < 8; ++q) { float b = b2[j0 + q]; acc0[q] = b; acc1[q] = b; }
        for (int k = 0; k < HID; k += 4) {
            float4 a0 = *(const float4*)&sh1[s0 * AS + k];
            float4 a1 = *(const float4*)&sh1[(s0 + 1) * AS + k];
            const float* a0p = (const float*)&a0;
            const float* a1p = (const float*)&a1;
            #pragma unroll
            for (int kk = 0; kk < 4; ++kk) {
                const float* wr = W2 + (size_t)(k + kk) * HID + j0;
                float4 wA = *(const float4*)(wr);
                float4 wB = *(const float4*)(wr + 4);
                const float* wAp = (const float*)&wA;
                const float* wBp = (const float*)&wB;
                float a0v = a0p[kk], a1v = a1p[kk];
                #pragma unroll
                for (int q = 0; q < 4; ++q) {
                    acc0[q]     += a0v * wAp[q];
                    acc1[q]     += a1v * wAp[q];
                    acc0[4 + q] += a0v * wBp[q];
                    acc1[4 + q] += a1v * wBp[q];
                }
            }
        }
        #pragma unroll
        for (int q = 0; q < 8; ++q) {
            sh2[s0 * AS + j0 + q]       = fmaxf(acc0[q], 0.f);
            sh2[(s0 + 1) * AS + j0 + q] = fmaxf(acc1[q], 0.f);
        }
    }
    __syncthreads();

    // ---- Phase 3: p = h2 @ W3 + b3  (128 -> 141), 2 samples x 9 cols per thread (16*9=144 >= 141) ----
    {
        const int jt = tid & 15, st = tid >> 4;
        const int j0 = jt * 9, s0 = st * 2;
        bool vmask[9];
        #pragma unroll
        for (int q = 0; q < 9; ++q) vmask[q] = (j0 + q) < OUTD;
        float acc0[9], acc1[9];
        #pragma unroll
        for (int q = 0; q < 9; ++q) {
            float b = vmask[q] ? b3[j0 + q] : 0.f;
            acc0[q] = b; acc1[q] = b;
        }
        for (int k = 0; k < HID; k += 4) {
            float4 a0 = *(const float4*)&sh2[s0 * AS + k];
            float4 a1 = *(const float4*)&sh2[(s0 + 1) * AS + k];
            const float* a0p = (const float*)&a0;
            const float* a1p = (const float*)&a1;
            #pragma unroll
            for (int kk = 0; kk < 4; ++kk) {
                const float* wr = W3 + (size_t)(k + kk) * OUTD + j0;
                float a0v = a0p[kk], a1v = a1p[kk];
                #pragma unroll
                for (int q = 0; q < 9; ++q) {
                    float w = vmask[q] ? wr[q] : 0.f;
                    acc0[q] += a0v * w;
                    acc1[q] += a1v * w;
                }
            }
        }
        #pragma unroll
        for (int q = 0; q < 9; ++q) {
            if (vmask[q]) {
                shp[s0 * PS + j0 + q]       = acc0[q];
                shp[(s0 + 1) * PS + j0 + q] = acc1[q];
            }
        }
    }
    __syncthreads();

    // ---- Phase 4: per (sample, dim): softmax -> cumsum -> bin scan -> RQS ----
    if (tid < TILE * 3) {
        const int s = tid / 3, d = tid - s * 3;
        const int g = g0 + s;
        if (g < N) {
            const float* pr = &shp[s * PS + d * 47];
            float wv[16], hv[16];
            float mw = -1e30f, mh = -1e30f;
            #pragma unroll
            for (int i = 0; i < 16; ++i) { wv[i] = pr[i];      mw = fmaxf(mw, wv[i]); }
            #pragma unroll
            for (int i = 0; i < 16; ++i) { hv[i] = pr[16 + i]; mh = fmaxf(mh, hv[i]); }
            float sw = 0.f, sh = 0.f;
            #pragma unroll
            for (int i = 0; i < 16; ++i) { wv[i] = __expf(wv[i] - mw); sw += wv[i]; }
            #pragma unroll
            for (int i = 0; i < 16; ++i) { hv[i] = __expf(hv[i] - mh); sh += hv[i]; }
            float cwn = 10.f / sw, chn = 10.f / sh;
            #pragma unroll
            for (int i = 0; i < 16; ++i) { wv[i] *= cwn; hv[i] *= chn; }
            float dv[15];
            #pragma unroll
            for (int i = 0; i < 15; ++i) {
                float t = pr[32 + i];
                dv[i] = (t > 15.f) ? t : log1pf(__expf(t));   // softplus
            }

            float xv = x[g * 6 + d];
            bool oob = (xv <= -BND) || (xv >= BND);
            float xm = oob ? -BND : xv;

            // scan interior edges xk[1..15]; select bin quantities (all static indices)
            float cumx = -BND + wv[0], cumy = -BND + hv[0];   // xk[1], yk[1]
            float xk_b = -BND, yk_b = -BND;
            float wk = wv[0], hk = hv[0];
            float d0 = 1.f, d1 = dv[0];
            #pragma unroll
            for (int i = 1; i < 16; ++i) {
                bool ge = (xm >= cumx);
                if (ge) {
                    xk_b = cumx; yk_b = cumy;
                    wk = wv[i]; hk = hv[i];
                    d0 = dv[i - 1];
                    d1 = (i < 15) ? dv[i] : 1.f;
                }
                cumx += wv[i]; cumy += hv[i];
            }

            float sk = hk / wk;
            float relx = (xm - xk_b) / wk;
            relx = fminf(fmaxf(relx, 0.f), 1.f);
            float r1 = relx * (1.f - relx);
            float den = sk + (d1 + d0 - 2.f * sk) * r1;
            float num = hk * (sk * relx * relx + d0 * r1);
            float y = yk_b + num / den;
            float omr = 1.f - relx;
            float ld = 2.f * __logf(sk)
                     + __logf(d1 * relx * relx + 2.f * sk * r1 + d0 * omr * omr)
                     - 2.f * __logf(den);
            if (oob) { y = xv; ld = 0.f; }

            out_y[g * 6 + d] = y;
            out_y[g * 6 + 3 + d] = x[g * 6 + 3 + d];   // upper pass-through
            shld[s * 3 + d] = ld;
        } else {
            shld[s * 3 + d] = 0.f;
        }
    }
    __syncthreads();

    // ---- Phase 5: reduce log-det over the 3 dims ----
    if (tid < TILE) {
        int g = g0 + tid;
        if (g < N)
            out_ld[g] = shld[tid * 3] + shld[tid * 3 + 1] + shld[tid * 3 + 2];
    }
}

extern "C" void kernel_launch(void* const* d_in, const int* in_sizes, int n_in,
                              void* d_out, int out_size, void* d_ws, size_t ws_size,
                              hipStream_t stream) {
    const float* x  = (const float*)d_in[0];
    const float* c  = (const float*)d_in[1];
    const float* W1 = (const float*)d_in[2];
    const float* b1 = (const float*)d_in[3];
    const float* W2 = (const float*)d_in[4];
    const float* b2 = (const float*)d_in[5];
    const float* W3 = (const float*)d_in[6];
    const float* b3 = (const float*)d_in[7];
    // d_in[8] = train flag (unused; inference path only)

    const int N = in_sizes[0] / 6;              // 500000
    float* out_y  = (float*)d_out;
    float* out_ld = (float*)d_out + (size_t)N * 6;

    int nblocks = (N + TILE - 1) / TILE;        // 15625
    nsc_fused_kernel<<<nblocks, NT, 0, stream>>>(x, c, W1, b1, W2, b2, W3, b3,
                                                 out_y, out_ld, N);
}

// Round 2
// 1387.296 us; speedup vs baseline: 1.4494x; 1.4494x over previous
//
#include <hip/hip_runtime.h>
#include <math.h>

// NeuralSplineCoupling: y[:, :3] = RQS(x[:, :3]; params = MLP([x[:,3:], c]))
//                       y[:, 3:] = x[:, 3:],  log_det = sum over 3 dims
// N = 500000, X_DIM=6, C_DIM=4, HID=128, KNOTS=16, SPLINE_DIM=47, OUT_DIM=141
//
// Round 2: TILE=64, 4 samples x 8/9 cols per thread, transposed LDS activations
// ([k][sample] -> ds_read_b128 across samples), W3 repacked col-major [144][128]
// in d_ws for dwordx4 weight loads. In-place h1->h2 LDS reuse (barrier-separated).

#define TILE 64
#define NT   256
#define HID  128
#define OUTD 141
#define AS   68      // shA row stride in floats (272 B, 16B-aligned rows)
#define PSS  148     // shp row stride in floats
#define BND  5.0f

__global__ void nsc_repack_w3(const float* __restrict__ W3, float* __restrict__ W3t) {
    int idx = blockIdx.x * 256 + threadIdx.x;      // idx = j*128 + k
    if (idx < 144 * 128) {
        int j = idx >> 7, k = idx & 127;
        W3t[idx] = (j < OUTD) ? W3[k * OUTD + j] : 0.f;
    }
}

__global__ __launch_bounds__(NT) void nsc_main(
    const float* __restrict__ x, const float* __restrict__ c,
    const float* __restrict__ W1, const float* __restrict__ b1,
    const float* __restrict__ W2, const float* __restrict__ b2,
    const float* __restrict__ W3t, const float* __restrict__ b3,
    float* __restrict__ out_y, float* __restrict__ out_ld, int N)
{
    __shared__ float shA[128 * AS];   // activations transposed: [feature k][sample] (h1 then h2)
    __shared__ float shp[TILE * PSS]; // spline params p: [sample][141]
    __shared__ float shin[TILE * 8];  // staged inputs; reused for per-dim log-det later

    const int tid = threadIdx.x;
    const int g0 = blockIdx.x * TILE;

    // ---- Phase 0: stage h = [x_upper(3), c(4), 0] ----
    for (int idx = tid; idx < TILE * 8; idx += NT) {
        int s = idx >> 3, k = idx & 7;
        int g = g0 + s;
        float v = 0.f;
        if (g < N && k < 7) v = (k < 3) ? x[g * 6 + 3 + k] : c[g * 4 + (k - 3)];
        shin[idx] = v;
    }
    __syncthreads();

    // ---- Phase 1: h1 = relu(h @ W1 + b1), stored transposed shA[j][s] ----
    {
        const int j = tid & 127;
        const int sb = tid >> 7;             // 0 or 1
        float w[7];
        #pragma unroll
        for (int k = 0; k < 7; ++k) w[k] = W1[k * HID + j];
        const float bj = b1[j];
        #pragma unroll
        for (int i = 0; i < TILE / 2; ++i) {
            int s = sb + 2 * i;
            float a = bj;
            #pragma unroll
            for (int k = 0; k < 7; ++k) a += shin[s * 8 + k] * w[k];
            shA[j * AS + s] = fmaxf(a, 0.f);
        }
    }
    __syncthreads();

    const int cg = tid & 15;          // col group
    const int sg = tid >> 4;          // sample group, 0..15
    const int s0 = sg * 4;

    // ---- Phase 2: h2 = relu(h1 @ W2 + b2); thread tile 4 samples x 8 cols ----
    float acc2[8][4];
    {
        const int j0 = cg * 8;
        #pragma unroll
        for (int q = 0; q < 8; ++q) {
            float b = b2[j0 + q];
            #pragma unroll
            for (int ss = 0; ss < 4; ++ss) acc2[q][ss] = b;
        }
        #pragma unroll 4
        for (int k = 0; k < HID; ++k) {
            float4 a  = *(const float4*)&shA[k * AS + s0];
            const float* wr = W2 + (size_t)k * HID + j0;
            float4 w0 = *(const float4*)(wr);
            float4 w1 = *(const float4*)(wr + 4);
            const float* ap  = (const float*)&a;
            const float* w0p = (const float*)&w0;
            const float* w1p = (const float*)&w1;
            #pragma unroll
            for (int q = 0; q < 4; ++q) {
                #pragma unroll
                for (int ss = 0; ss < 4; ++ss) {
                    acc2[q][ss]     += ap[ss] * w0p[q];
                    acc2[4 + q][ss] += ap[ss] * w1p[q];
                }
            }
        }
    }
    __syncthreads();   // all reads of h1 complete before overwrite
    {
        const int j0 = cg * 8;
        #pragma unroll
        for (int q = 0; q < 8; ++q)
            #pragma unroll
            for (int ss = 0; ss < 4; ++ss)
                shA[(j0 + q) * AS + s0 + ss] = fmaxf(acc2[q][ss], 0.f);
    }
    __syncthreads();

    // ---- Phase 3: p = h2 @ W3 + b3; thread tile 4 samples x 9 cols (16*9=144) ----
    {
        const int j3 = cg * 9;
        float acc3[9][4];
        #pragma unroll
        for (int q = 0; q < 9; ++q) {
            float b = (j3 + q < OUTD) ? b3[j3 + q] : 0.f;
            #pragma unroll
            for (int ss = 0; ss < 4; ++ss) acc3[q][ss] = b;
        }
        for (int k = 0; k < HID; k += 4) {
            float4 a0 = *(const float4*)&shA[(k + 0) * AS + s0];
            float4 a1 = *(const float4*)&shA[(k + 1) * AS + s0];
            float4 a2 = *(const float4*)&shA[(k + 2) * AS + s0];
            float4 a3 = *(const float4*)&shA[(k + 3) * AS + s0];
            const float* a0p = (const float*)&a0;
            const float* a1p = (const float*)&a1;
            const float* a2p = (const float*)&a2;
            const float* a3p = (const float*)&a3;
            #pragma unroll
            for (int q = 0; q < 9; ++q) {
                float4 w = *(const float4*)&W3t[(size_t)(j3 + q) * HID + k];
                const float* wp = (const float*)&w;
                #pragma unroll
                for (int ss = 0; ss < 4; ++ss) {
                    acc3[q][ss] += a0p[ss] * wp[0];
                    acc3[q][ss] += a1p[ss] * wp[1];
                    acc3[q][ss] += a2p[ss] * wp[2];
                    acc3[q][ss] += a3p[ss] * wp[3];
                }
            }
        }
        #pragma unroll
        for (int q = 0; q < 9; ++q) {
            if (j3 + q < OUTD) {
                #pragma unroll
                for (int ss = 0; ss < 4; ++ss)
                    shp[(s0 + ss) * PSS + j3 + q] = acc3[q][ss];
            }
        }
    }
    __syncthreads();

    // ---- Phase 4: per (sample, dim): softmax -> cumsum -> bin scan -> RQS ----
    // shin reused as per-dim log-det storage (192 floats needed, 512 available)
    if (tid < TILE * 3) {
        const int s = tid / 3, d = tid - s * 3;
        const int g = g0 + s;
        if (g < N) {
            const float* pr = &shp[s * PSS + d * 47];
            float wv[16], hv[16];
            float mw = -1e30f, mh = -1e30f;
            #pragma unroll
            for (int i = 0; i < 16; ++i) { wv[i] = pr[i];      mw = fmaxf(mw, wv[i]); }
            #pragma unroll
            for (int i = 0; i < 16; ++i) { hv[i] = pr[16 + i]; mh = fmaxf(mh, hv[i]); }
            float sw = 0.f, sh = 0.f;
            #pragma unroll
            for (int i = 0; i < 16; ++i) { wv[i] = __expf(wv[i] - mw); sw += wv[i]; }
            #pragma unroll
            for (int i = 0; i < 16; ++i) { hv[i] = __expf(hv[i] - mh); sh += hv[i]; }
            float cwn = 10.f / sw, chn = 10.f / sh;
            #pragma unroll
            for (int i = 0; i < 16; ++i) { wv[i] *= cwn; hv[i] *= chn; }
            float dv[15];
            #pragma unroll
            for (int i = 0; i < 15; ++i) {
                float t = pr[32 + i];
                dv[i] = (t > 15.f) ? t : log1pf(__expf(t));   // softplus
            }

            float xv = x[g * 6 + d];
            bool oob = (xv <= -BND) || (xv >= BND);
            float xm = oob ? -BND : xv;

            float cumx = -BND + wv[0], cumy = -BND + hv[0];
            float xk_b = -BND, yk_b = -BND;
            float wk = wv[0], hk = hv[0];
            float d0 = 1.f, d1 = dv[0];
            #pragma unroll
            for (int i = 1; i < 16; ++i) {
                bool ge = (xm >= cumx);
                if (ge) {
                    xk_b = cumx; yk_b = cumy;
                    wk = wv[i]; hk = hv[i];
                    d0 = dv[i - 1];
                    d1 = (i < 15) ? dv[i] : 1.f;
                }
                cumx += wv[i]; cumy += hv[i];
            }

            float sk = hk / wk;
            float relx = (xm - xk_b) / wk;
            relx = fminf(fmaxf(relx, 0.f), 1.f);
            float r1 = relx * (1.f - relx);
            float den = sk + (d1 + d0 - 2.f * sk) * r1;
            float num = hk * (sk * relx * relx + d0 * r1);
            float y = yk_b + num / den;
            float omr = 1.f - relx;
            float ld = 2.f * __logf(sk)
                     + __logf(d1 * relx * relx + 2.f * sk * r1 + d0 * omr * omr)
                     - 2.f * __logf(den);
            if (oob) { y = xv; ld = 0.f; }

            out_y[g * 6 + d] = y;
            out_y[g * 6 + 3 + d] = x[g * 6 + 3 + d];   // upper pass-through
            shin[s * 3 + d] = ld;
        } else {
            shin[s * 3 + d] = 0.f;
        }
    }
    __syncthreads();

    // ---- Phase 5: reduce log-det over the 3 dims ----
    if (tid < TILE) {
        int g = g0 + tid;
        if (g < N)
            out_ld[g] = shin[tid * 3] + shin[tid * 3 + 1] + shin[tid * 3 + 2];
    }
}

extern "C" void kernel_launch(void* const* d_in, const int* in_sizes, int n_in,
                              void* d_out, int out_size, void* d_ws, size_t ws_size,
                              hipStream_t stream) {
    const float* x  = (const float*)d_in[0];
    const float* c  = (const float*)d_in[1];
    const float* W1 = (const float*)d_in[2];
    const float* b1 = (const float*)d_in[3];
    const float* W2 = (const float*)d_in[4];
    const float* b2 = (const float*)d_in[5];
    const float* W3 = (const float*)d_in[6];
    const float* b3 = (const float*)d_in[7];

    const int N = in_sizes[0] / 6;              // 500000
    float* out_y  = (float*)d_out;
    float* out_ld = (float*)d_out + (size_t)N * 6;

    float* W3t = (float*)d_ws;                  // 144*128*4 = 73728 B

    nsc_repack_w3<<<(144 * 128 + 255) / 256, 256, 0, stream>>>(W3, W3t);

    int nblocks = (N + TILE - 1) / TILE;        // 7813
    nsc_main<<<nblocks, NT, 0, stream>>>(x, c, W1, b1, W2, b2, W3t, b3,
                                         out_y, out_ld, N);
}

// Round 3
// 283.258 us; speedup vs baseline: 7.0989x; 4.8976x over previous
//
#include <hip/hip_runtime.h>
#include <math.h>

// NeuralSplineCoupling: y[:, :3] = RQS(x[:, :3]; params = MLP([x[:,3:], c]))
//                       y[:, 3:] = x[:, 3:],  log_det = sum over 3 dims
// N = 500000, X_DIM=6, C_DIM=4, HID=128, KNOTS=16, SPLINE_DIM=47, OUT_DIM=141
//
// Round 3: phases 2/3 on bf16 MFMA (16x16x32). Weights prepacked per-launch
// into B-fragment order in d_ws (bf16); activations staged bf16 in LDS rows
// readable as A-fragments (one ds_read_b128 per k-step). fp32 MFMA accumulate;
// spline phase unchanged fp32.

#define TILE 64
#define NT   256
#define HID  128
#define OUTD 141
#define HS   136     // bf16 LDS row stride (272 B: 16B-aligned, 2-way-free banks)
#define PSS  148     // fp32 LDS row stride for p
#define BND  5.0f

typedef __bf16 bf16;
typedef __attribute__((ext_vector_type(8))) __bf16 bf16x8;
typedef __attribute__((ext_vector_type(4))) float f32x4;

#define W2P_ELEMS (8 * 4 * 64 * 8)    // 8 n-tiles x 4 k-steps x 64 lanes x 8
#define W3P_ELEMS (9 * 4 * 64 * 8)    // 9 n-tiles (144 cols, padded)

// Pack W2/W3 (fp32 row-major) into bf16 MFMA B-fragment order:
// frag element j of lane l, tile t, k-step ks  <->  B[k = ks*32+(l>>4)*8+j][n = t*16+(l&15)]
__global__ void nsc_prepack(const float* __restrict__ W2, const float* __restrict__ W3,
                            bf16* __restrict__ W2p, bf16* __restrict__ W3p) {
    int t = blockIdx.x * 256 + threadIdx.x;
    if (t < W2P_ELEMS) {
        int j = t & 7, l = (t >> 3) & 63, ks = (t >> 9) & 3, t2 = t >> 11;
        int k = ks * 32 + (l >> 4) * 8 + j;
        int n = t2 * 16 + (l & 15);
        W2p[t] = (bf16)W2[k * HID + n];
    } else if (t < W2P_ELEMS + W3P_ELEMS) {
        int u = t - W2P_ELEMS;
        int j = u & 7, l = (u >> 3) & 63, ks = (u >> 9) & 3, t3 = u >> 11;
        int k = ks * 32 + (l >> 4) * 8 + j;
        int col = t3 * 16 + (l & 15);
        W3p[u] = (col < OUTD) ? (bf16)W3[k * OUTD + col] : (bf16)0.f;
    }
}

__global__ __launch_bounds__(NT) void nsc_main(
    const float* __restrict__ x, const float* __restrict__ c,
    const float* __restrict__ W1, const float* __restrict__ b1,
    const bf16* __restrict__ W2p, const float* __restrict__ b2,
    const bf16* __restrict__ W3p, const float* __restrict__ b3,
    float* __restrict__ out_y, float* __restrict__ out_ld, int N)
{
    __shared__ bf16  h1a[TILE * HS];   // h1, A-fragment-readable rows [s][k]
    __shared__ bf16  h2a[TILE * HS];   // h2, same layout
    __shared__ float shp[TILE * PSS];  // spline params p (fp32)
    __shared__ float shin[TILE * 8];   // staged inputs; reused for log-det

    const int tid = threadIdx.x;
    const int g0 = blockIdx.x * TILE;

    // ---- Phase 0: stage h = [x_upper(3), c(4), 0] ----
    for (int idx = tid; idx < TILE * 8; idx += NT) {
        int s = idx >> 3, k = idx & 7;
        int g = g0 + s;
        float v = 0.f;
        if (g < N && k < 7) v = (k < 3) ? x[g * 6 + 3 + k] : c[g * 4 + (k - 3)];
        shin[idx] = v;
    }
    __syncthreads();

    // ---- Phase 1: h1 = relu(h @ W1 + b1) -> bf16 LDS rows ----
    {
        const int j = tid & 127;
        const int sb = tid >> 7;
        float w[7];
        #pragma unroll
        for (int k = 0; k < 7; ++k) w[k] = W1[k * HID + j];
        const float bj = b1[j];
        #pragma unroll
        for (int i = 0; i < TILE / 2; ++i) {
            int s = sb + 2 * i;
            float a = bj;
            #pragma unroll
            for (int k = 0; k < 7; ++k) a += shin[s * 8 + k] * w[k];
            h1a[s * HS + j] = (bf16)fmaxf(a, 0.f);
        }
    }
    __syncthreads();

    const int lane = tid & 63;
    const int wv   = tid >> 6;        // wave id = m-block (16 samples)
    const int lm   = lane & 15;
    const int lq   = lane >> 4;
    const int arow = wv * 16 + lm;    // A-fragment row for this lane

    // ---- Phase 2: h2 = relu(h1 @ W2 + b2) via MFMA; wave handles 16 samples x 128 cols ----
    f32x4 acc2[8];
    #pragma unroll
    for (int t2 = 0; t2 < 8; ++t2) {
        float b = b2[t2 * 16 + lm];
        acc2[t2] = (f32x4){b, b, b, b};
    }
    #pragma unroll
    for (int ks = 0; ks < 4; ++ks) {
        bf16x8 a = *(const bf16x8*)&h1a[arow * HS + ks * 32 + lq * 8];
        #pragma unroll
        for (int t2 = 0; t2 < 8; ++t2) {
            bf16x8 bf = *(const bf16x8*)&W2p[(size_t)((t2 * 4 + ks) * 64 + lane) * 8];
            acc2[t2] = __builtin_amdgcn_mfma_f32_16x16x32_bf16(a, bf, acc2[t2], 0, 0, 0);
        }
    }
    // epilogue: relu -> bf16 -> h2a. D layout: row m = lq*4+r, col n = t2*16+lm.
    // Rows wv*16..wv*16+15 are written and later read ONLY by this wave -> no barrier.
    #pragma unroll
    for (int t2 = 0; t2 < 8; ++t2) {
        #pragma unroll
        for (int r = 0; r < 4; ++r) {
            int s = wv * 16 + lq * 4 + r;
            h2a[s * HS + t2 * 16 + lm] = (bf16)fmaxf(acc2[t2][r], 0.f);
        }
    }

    // ---- Phase 3: p = h2 @ W3 + b3 via MFMA; 16 samples x 144 cols (141 valid) ----
    f32x4 acc3[9];
    #pragma unroll
    for (int t3 = 0; t3 < 9; ++t3) {
        int col = t3 * 16 + lm;
        float b = (col < OUTD) ? b3[col] : 0.f;
        acc3[t3] = (f32x4){b, b, b, b};
    }
    #pragma unroll
    for (int ks = 0; ks < 4; ++ks) {
        bf16x8 a = *(const bf16x8*)&h2a[arow * HS + ks * 32 + lq * 8];
        #pragma unroll
        for (int t3 = 0; t3 < 9; ++t3) {
            bf16x8 bf = *(const bf16x8*)&W3p[(size_t)((t3 * 4 + ks) * 64 + lane) * 8];
            acc3[t3] = __builtin_amdgcn_mfma_f32_16x16x32_bf16(a, bf, acc3[t3], 0, 0, 0);
        }
    }
    #pragma unroll
    for (int t3 = 0; t3 < 9; ++t3) {
        int col = t3 * 16 + lm;
        if (col < OUTD) {
            #pragma unroll
            for (int r = 0; r < 4; ++r) {
                int s = wv * 16 + lq * 4 + r;
                shp[s * PSS + col] = acc3[t3][r];
            }
        }
    }
    __syncthreads();

    // ---- Phase 4: per (sample, dim): softmax -> cumsum -> bin scan -> RQS ----
    if (tid < TILE * 3) {
        const int s = tid / 3, d = tid - s * 3;
        const int g = g0 + s;
        if (g < N) {
            const float* pr = &shp[s * PSS + d * 47];
            float wv_[16], hv[16];
            float mw = -1e30f, mh = -1e30f;
            #pragma unroll
            for (int i = 0; i < 16; ++i) { wv_[i] = pr[i];      mw = fmaxf(mw, wv_[i]); }
            #pragma unroll
            for (int i = 0; i < 16; ++i) { hv[i]  = pr[16 + i]; mh = fmaxf(mh, hv[i]); }
            float sw = 0.f, sh = 0.f;
            #pragma unroll
            for (int i = 0; i < 16; ++i) { wv_[i] = __expf(wv_[i] - mw); sw += wv_[i]; }
            #pragma unroll
            for (int i = 0; i < 16; ++i) { hv[i]  = __expf(hv[i]  - mh); sh += hv[i]; }
            float cwn = 10.f / sw, chn = 10.f / sh;
            #pragma unroll
            for (int i = 0; i < 16; ++i) { wv_[i] *= cwn; hv[i] *= chn; }
            float dv[15];
            #pragma unroll
            for (int i = 0; i < 15; ++i) {
                float t = pr[32 + i];
                dv[i] = (t > 15.f) ? t : log1pf(__expf(t));   // softplus
            }

            float xv = x[g * 6 + d];
            bool oob = (xv <= -BND) || (xv >= BND);
            float xm = oob ? -BND : xv;

            float cumx = -BND + wv_[0], cumy = -BND + hv[0];
            float xk_b = -BND, yk_b = -BND;
            float wk = wv_[0], hk = hv[0];
            float d0 = 1.f, d1 = dv[0];
            #pragma unroll
            for (int i = 1; i < 16; ++i) {
                bool ge = (xm >= cumx);
                if (ge) {
                    xk_b = cumx; yk_b = cumy;
                    wk = wv_[i]; hk = hv[i];
                    d0 = dv[i - 1];
                    d1 = (i < 15) ? dv[i] : 1.f;
                }
                cumx += wv_[i]; cumy += hv[i];
            }

            float sk = hk / wk;
            float relx = (xm - xk_b) / wk;
            relx = fminf(fmaxf(relx, 0.f), 1.f);
            float r1 = relx * (1.f - relx);
            float den = sk + (d1 + d0 - 2.f * sk) * r1;
            float num = hk * (sk * relx * relx + d0 * r1);
            float y = yk_b + num / den;
            float omr = 1.f - relx;
            float ld = 2.f * __logf(sk)
                     + __logf(d1 * relx * relx + 2.f * sk * r1 + d0 * omr * omr)
                     - 2.f * __logf(den);
            if (oob) { y = xv; ld = 0.f; }

            out_y[g * 6 + d] = y;
            out_y[g * 6 + 3 + d] = x[g * 6 + 3 + d];   // upper pass-through
            shin[s * 3 + d] = ld;
        } else {
            shin[s * 3 + d] = 0.f;
        }
    }
    __syncthreads();

    // ---- Phase 5: reduce log-det over the 3 dims ----
    if (tid < TILE) {
        int g = g0 + tid;
        if (g < N)
            out_ld[g] = shin[tid * 3] + shin[tid * 3 + 1] + shin[tid * 3 + 2];
    }
}

extern "C" void kernel_launch(void* const* d_in, const int* in_sizes, int n_in,
                              void* d_out, int out_size, void* d_ws, size_t ws_size,
                              hipStream_t stream) {
    const float* x  = (const float*)d_in[0];
    const float* c  = (const float*)d_in[1];
    const float* W1 = (const float*)d_in[2];
    const float* b1 = (const float*)d_in[3];
    const float* W2 = (const float*)d_in[4];
    const float* b2 = (const float*)d_in[5];
    const float* W3 = (const float*)d_in[6];
    const float* b3 = (const float*)d_in[7];

    const int N = in_sizes[0] / 6;              // 500000
    float* out_y  = (float*)d_out;
    float* out_ld = (float*)d_out + (size_t)N * 6;

    bf16* W2p = (bf16*)d_ws;                         // 32768 B
    bf16* W3p = (bf16*)d_ws + W2P_ELEMS;             // 36864 B

    int total = W2P_ELEMS + W3P_ELEMS;
    nsc_prepack<<<(total + 255) / 256, 256, 0, stream>>>(W2, W3, W2p, W3p);

    int nblocks = (N + TILE - 1) / TILE;        // 7813
    nsc_main<<<nblocks, NT, 0, stream>>>(x, c, W1, b1, W2p, b2, W3p, b3,
                                         out_y, out_ld, N);
}

// Round 4
// 195.784 us; speedup vs baseline: 10.2706x; 1.4468x over previous
//
#include <hip/hip_runtime.h>
#include <math.h>

// NeuralSplineCoupling: y[:, :3] = RQS(x[:, :3]; params = MLP([x[:,3:], c]))
//                       y[:, 3:] = x[:, 3:],  log_det = sum over 3 dims
// N = 500000, X_DIM=6, C_DIM=4, HID=128, KNOTS=16, SPLINE_DIM=47, OUT_DIM=141
//
// Round 4: all three layers on bf16 MFMA (layer 1: K padded 7->32 with zeros,
// bias folded into acc). All h traffic is wave-private LDS rows -> no barriers
// through phases 0-3. LDS shrunk to ~37.6 KB (shp aliases shIn+h via one char
// buffer, barrier-protected) -> 4 blocks/CU. Spline: fast softplus, no
// max-subtract, p stored [s][d][48] for ds_read_b128.

#define TILE 64
#define NT   256
#define HID  128
#define OUTD 141
#define INS  40      // shIn row stride (bf16): 80 B, 16B-aligned, banks rotate by 20
#define HS   136     // h row stride (bf16): 272 B, banks rotate by 4 (2-way free)
#define PRS  48      // floats per (sample,dim) p row (47 used, 16B-aligned)
#define SRS  144     // floats per sample (3*48)
#define BND  5.0f

typedef __bf16 bf16;
typedef __attribute__((ext_vector_type(8))) __bf16 bf16x8;
typedef __attribute__((ext_vector_type(4))) float f32x4;

#define W1P_ELEMS (8 * 64 * 8)        // 8 n-tiles x 1 k-step
#define W2P_ELEMS (8 * 4 * 64 * 8)    // 8 n-tiles x 4 k-steps
#define W3P_ELEMS (9 * 4 * 64 * 8)    // 9 n-tiles x 4 k-steps (144 cols, padded)

// LDS layout (bytes):  [0,5120) shIn | [5120,22528) h (h1 then h2 in place)
// shp [0,36864) ALIASES shIn+h (barrier-separated) | shld [36864,37632)
#define SMEM_BYTES 37632

// Pack weights (fp32 row-major) into bf16 MFMA B-fragment order:
// elem j of lane l, tile t, k-step ks  <->  B[k = ks*32+(l>>4)*8+j][n = t*16+(l&15)]
__global__ void nsc_prepack(const float* __restrict__ W1, const float* __restrict__ W2,
                            const float* __restrict__ W3,
                            bf16* __restrict__ W1p, bf16* __restrict__ W2p,
                            bf16* __restrict__ W3p) {
    int t = blockIdx.x * 256 + threadIdx.x;
    if (t < W1P_ELEMS) {
        int j = t & 7, l = (t >> 3) & 63, t1 = t >> 9;
        int k = (l >> 4) * 8 + j;          // ks = 0 only; valid k < 7
        int n = t1 * 16 + (l & 15);
        W1p[t] = (k < 7) ? (bf16)W1[k * HID + n] : (bf16)0.f;
    } else if (t < W1P_ELEMS + W2P_ELEMS) {
        int u = t - W1P_ELEMS;
        int j = u & 7, l = (u >> 3) & 63, ks = (u >> 9) & 3, t2 = u >> 11;
        int k = ks * 32 + (l >> 4) * 8 + j;
        int n = t2 * 16 + (l & 15);
        W2p[u] = (bf16)W2[k * HID + n];
    } else if (t < W1P_ELEMS + W2P_ELEMS + W3P_ELEMS) {
        int u = t - W1P_ELEMS - W2P_ELEMS;
        int j = u & 7, l = (u >> 3) & 63, ks = (u >> 9) & 3, t3 = u >> 11;
        int k = ks * 32 + (l >> 4) * 8 + j;
        int col = t3 * 16 + (l & 15);
        W3p[u] = (col < OUTD) ? (bf16)W3[k * OUTD + col] : (bf16)0.f;
    }
}

__global__ __launch_bounds__(NT) void nsc_main(
    const float* __restrict__ x, const float* __restrict__ c,
    const bf16* __restrict__ W1p, const float* __restrict__ b1,
    const bf16* __restrict__ W2p, const float* __restrict__ b2,
    const bf16* __restrict__ W3p, const float* __restrict__ b3,
    float* __restrict__ out_y, float* __restrict__ out_ld, int N)
{
    __shared__ __align__(16) char smem[SMEM_BYTES];
    bf16*  shIn = (bf16*)smem;                  // [s][INS]
    bf16*  hbuf = (bf16*)(smem + 5120);         // [s][HS]
    float* shp  = (float*)smem;                 // [s][3][PRS]  (aliases above)
    float* shld = (float*)(smem + 36864);       // [s][3]

    const int tid  = threadIdx.x;
    const int g0   = blockIdx.x * TILE;
    const int lane = tid & 63;
    const int wv   = tid >> 6;        // wave id; owns samples wv*16 .. wv*16+15
    const int lm   = lane & 15;
    const int lq   = lane >> 4;
    const int arow = wv * 16 + lm;    // A-fragment row (sample) for this lane

    // ---- Phase 0: stage inputs bf16, A-frag rows, zero-padded K=32 (wave-private) ----
    if (lm == 0 || lq == 0) { /* keep all lanes converged; work below masks itself */ }
    {
        if (lane < 16) {
            int s = wv * 16 + lane;
            int g = g0 + s;
            float v[7];
            if (g < N) {
                v[0] = x[g * 6 + 3]; v[1] = x[g * 6 + 4]; v[2] = x[g * 6 + 5];
                v[3] = c[g * 4];     v[4] = c[g * 4 + 1];
                v[5] = c[g * 4 + 2]; v[6] = c[g * 4 + 3];
            } else {
                #pragma unroll
                for (int k = 0; k < 7; ++k) v[k] = 0.f;
            }
            bf16* row = &shIn[s * INS];
            #pragma unroll
            for (int k = 0; k < 7; ++k) row[k] = (bf16)v[k];
            #pragma unroll
            for (int k = 7; k < 32; ++k) row[k] = (bf16)0.f;
        }
    }
    // no barrier: wave reads only its own rows, DS ops are in-order per wave

    // ---- Phase 1: h1 = relu([h,0] @ W1 + b1) via MFMA (1 k-step) ----
    {
        f32x4 acc1[8];
        #pragma unroll
        for (int t = 0; t < 8; ++t) {
            float b = b1[t * 16 + lm];
            acc1[t] = (f32x4){b, b, b, b};
        }
        bf16x8 a = *(const bf16x8*)&shIn[arow * INS + lq * 8];
        #pragma unroll
        for (int t = 0; t < 8; ++t) {
            bf16x8 bf = *(const bf16x8*)&W1p[(size_t)(t * 64 + lane) * 8];
            acc1[t] = __builtin_amdgcn_mfma_f32_16x16x32_bf16(a, bf, acc1[t], 0, 0, 0);
        }
        #pragma unroll
        for (int t = 0; t < 8; ++t)
            #pragma unroll
            for (int r = 0; r < 4; ++r) {
                int s = wv * 16 + lq * 4 + r;
                hbuf[s * HS + t * 16 + lm] = (bf16)fmaxf(acc1[t][r], 0.f);
            }
    }

    // ---- Phase 2: h2 = relu(h1 @ W2 + b2) via MFMA; in-place h overwrite ----
    {
        f32x4 acc2[8];
        #pragma unroll
        for (int t = 0; t < 8; ++t) {
            float b = b2[t * 16 + lm];
            acc2[t] = (f32x4){b, b, b, b};
        }
        #pragma unroll
        for (int ks = 0; ks < 4; ++ks) {
            bf16x8 a = *(const bf16x8*)&hbuf[arow * HS + ks * 32 + lq * 8];
            #pragma unroll
            for (int t = 0; t < 8; ++t) {
                bf16x8 bf = *(const bf16x8*)&W2p[(size_t)((t * 4 + ks) * 64 + lane) * 8];
                acc2[t] = __builtin_amdgcn_mfma_f32_16x16x32_bf16(a, bf, acc2[t], 0, 0, 0);
            }
        }
        // all reads of this wave's rows precede these writes (in-order DS per wave)
        #pragma unroll
        for (int t = 0; t < 8; ++t)
            #pragma unroll
            for (int r = 0; r < 4; ++r) {
                int s = wv * 16 + lq * 4 + r;
                hbuf[s * HS + t * 16 + lm] = (bf16)fmaxf(acc2[t][r], 0.f);
            }
    }

    // ---- Phase 3: p = h2 @ W3 + b3 via MFMA ----
    f32x4 acc3[9];
    {
        #pragma unroll
        for (int t = 0; t < 9; ++t) {
            int col = t * 16 + lm;
            float b = (col < OUTD) ? b3[col] : 0.f;
            acc3[t] = (f32x4){b, b, b, b};
        }
        #pragma unroll
        for (int ks = 0; ks < 4; ++ks) {
            bf16x8 a = *(const bf16x8*)&hbuf[arow * HS + ks * 32 + lq * 8];
            #pragma unroll
            for (int t = 0; t < 9; ++t) {
                bf16x8 bf = *(const bf16x8*)&W3p[(size_t)((t * 4 + ks) * 64 + lane) * 8];
                acc3[t] = __builtin_amdgcn_mfma_f32_16x16x32_bf16(a, bf, acc3[t], 0, 0, 0);
            }
        }
    }
    __syncthreads();   // every wave is done reading h/shIn -> shp may overwrite

    // epilogue: scatter p into [s][d][48] layout
    #pragma unroll
    for (int t = 0; t < 9; ++t) {
        int col = t * 16 + lm;
        if (col < OUTD) {
            int d = (col >= 94) ? 2 : ((col >= 47) ? 1 : 0);
            int i = col - d * 47;
            #pragma unroll
            for (int r = 0; r < 4; ++r) {
                int s = wv * 16 + lq * 4 + r;
                shp[s * SRS + d * PRS + i] = acc3[t][r];
            }
        }
    }
    __syncthreads();

    // ---- Phase 4: per (sample, dim): softmax -> cumsum -> bin scan -> RQS ----
    if (tid < TILE * 3) {
        const int s = tid / 3, d = tid - s * 3;
        const int g = g0 + s;
        if (g < N) {
            const float* pr = &shp[s * SRS + d * PRS];
            float wv_[16], hv[16], dl[16];
            #pragma unroll
            for (int q = 0; q < 4; ++q) {
                f32x4 v = *(const f32x4*)&pr[q * 4];
                wv_[q*4] = v[0]; wv_[q*4+1] = v[1]; wv_[q*4+2] = v[2]; wv_[q*4+3] = v[3];
            }
            #pragma unroll
            for (int q = 0; q < 4; ++q) {
                f32x4 v = *(const f32x4*)&pr[16 + q * 4];
                hv[q*4] = v[0]; hv[q*4+1] = v[1]; hv[q*4+2] = v[2]; hv[q*4+3] = v[3];
            }
            #pragma unroll
            for (int q = 0; q < 4; ++q) {
                f32x4 v = *(const f32x4*)&pr[32 + q * 4];
                dl[q*4] = v[0]; dl[q*4+1] = v[1]; dl[q*4+2] = v[2]; dl[q*4+3] = v[3];
            }
            // softmax without max-subtract: logits are O(1), exp overflow needs >88
            float sw = 0.f, sh = 0.f;
            #pragma unroll
            for (int i = 0; i < 16; ++i) { wv_[i] = __expf(wv_[i]); sw += wv_[i]; }
            #pragma unroll
            for (int i = 0; i < 16; ++i) { hv[i]  = __expf(hv[i]);  sh += hv[i]; }
            float cwn = 10.f / sw, chn = 10.f / sh;
            #pragma unroll
            for (int i = 0; i < 16; ++i) { wv_[i] *= cwn; hv[i] *= chn; }
            float dv[15];
            #pragma unroll
            for (int i = 0; i < 15; ++i) {
                float t = dl[i];
                dv[i] = (t > 15.f) ? t : __logf(1.f + __expf(t));   // fast softplus
            }

            float xv = x[g * 6 + d];
            bool oob = (xv <= -BND) || (xv >= BND);
            float xm = oob ? -BND : xv;

            float cumx = -BND + wv_[0], cumy = -BND + hv[0];
            float xk_b = -BND, yk_b = -BND;
            float wk = wv_[0], hk = hv[0];
            float d0 = 1.f, d1 = dv[0];
            #pragma unroll
            for (int i = 1; i < 16; ++i) {
                bool ge = (xm >= cumx);
                if (ge) {
                    xk_b = cumx; yk_b = cumy;
                    wk = wv_[i]; hk = hv[i];
                    d0 = dv[i - 1];
                    d1 = (i < 15) ? dv[i] : 1.f;
                }
                cumx += wv_[i]; cumy += hv[i];
            }

            float sk = hk / wk;
            float relx = (xm - xk_b) / wk;
            relx = fminf(fmaxf(relx, 0.f), 1.f);
            float r1 = relx * (1.f - relx);
            float den = sk + (d1 + d0 - 2.f * sk) * r1;
            float num = hk * (sk * relx * relx + d0 * r1);
            float y = yk_b + num / den;
            float omr = 1.f - relx;
            float ld = 2.f * __logf(sk)
                     + __logf(d1 * relx * relx + 2.f * sk * r1 + d0 * omr * omr)
                     - 2.f * __logf(den);
            if (oob) { y = xv; ld = 0.f; }

            out_y[g * 6 + d] = y;
            out_y[g * 6 + 3 + d] = x[g * 6 + 3 + d];   // upper pass-through (exact fp32)
            shld[s * 3 + d] = ld;
        } else {
            shld[s * 3 + d] = 0.f;
        }
    }
    __syncthreads();

    // ---- Phase 5: reduce log-det over the 3 dims ----
    if (tid < TILE) {
        int g = g0 + tid;
        if (g < N)
            out_ld[g] = shld[tid * 3] + shld[tid * 3 + 1] + shld[tid * 3 + 2];
    }
}

extern "C" void kernel_launch(void* const* d_in, const int* in_sizes, int n_in,
                              void* d_out, int out_size, void* d_ws, size_t ws_size,
                              hipStream_t stream) {
    const float* x  = (const float*)d_in[0];
    const float* c  = (const float*)d_in[1];
    const float* W1 = (const float*)d_in[2];
    const float* b1 = (const float*)d_in[3];
    const float* W2 = (const float*)d_in[4];
    const float* b2 = (const float*)d_in[5];
    const float* W3 = (const float*)d_in[6];
    const float* b3 = (const float*)d_in[7];

    const int N = in_sizes[0] / 6;              // 500000
    float* out_y  = (float*)d_out;
    float* out_ld = (float*)d_out + (size_t)N * 6;

    bf16* W1p = (bf16*)d_ws;                            //  8192 B
    bf16* W2p = W1p + W1P_ELEMS;                        // 32768 B
    bf16* W3p = W2p + W2P_ELEMS;                        // 36864 B

    int total = W1P_ELEMS + W2P_ELEMS + W3P_ELEMS;      // 38912
    nsc_prepack<<<(total + 255) / 256, 256, 0, stream>>>(W1, W2, W3, W1p, W2p, W3p);

    int nblocks = (N + TILE - 1) / TILE;                // 7813
    nsc_main<<<nblocks, NT, 0, stream>>>(x, c, W1p, b1, W2p, b2, W3p, b3,
                                         out_y, out_ld, N);
}

// Round 5
// 183.482 us; speedup vs baseline: 10.9592x; 1.0670x over previous
//
#include <hip/hip_runtime.h>
#include <math.h>

// NeuralSplineCoupling: y[:, :3] = RQS(x[:, :3]; params = MLP([x[:,3:], c]))
//                       y[:, 3:] = x[:, 3:],  log_det = sum over 3 dims
// N = 500000, X_DIM=6, C_DIM=4, HID=128, KNOTS=16, SPLINE_DIM=47, OUT_DIM=141
//
// Round 5: (a) k-permuted hidden storage: h stored at position p=lm*8+t so the
// MFMA D->A epilogue is 4x ds_write_b128 (was 32x ds_write_b16); W2/W3 packed
// with the matching k-permutation colmap(p)=(p&7)*16+(p>>3) (contraction is
// invariant to a shared k-permutation of A and B). (b) spline: softplus only
// for the 2 selected derivs (sentinel ln(e-1) at boundaries), single fused log
// for log-det, rcp for divides: 66 -> 37 transcendentals. (c) SRS 148 to
// de-bank-alias the phase-4 f32x4 p loads.

#define TILE 64
#define NT   256
#define HID  128
#define OUTD 141
#define INS  40      // shIn row stride (bf16)
#define HS   136     // h row stride (bf16): 272 B rows, 2-way banks (free)
#define PRS  48      // floats per (sample,dim) p row
#define SRS  148     // floats per sample in shp (4-float tail pad -> bank rotate 20)
#define BND  5.0f
#define T1   0.5413248546f   // ln(e-1): softplus(T1) = 1

typedef __bf16 bf16;
typedef __attribute__((ext_vector_type(8))) __bf16 bf16x8;
typedef __attribute__((ext_vector_type(4))) float f32x4;

#define W1P_ELEMS (8 * 64 * 8)        // identity k-map (features 0..6, rest zero)
#define W2P_ELEMS (8 * 4 * 64 * 8)    // colmap k-permuted
#define W3P_ELEMS (9 * 4 * 64 * 8)    // colmap k-permuted, 144 cols padded

// LDS: [0,5120) shIn | [5120,22528) hbuf ; shp [0,37888) aliases both
// (barrier-separated) | shld [37888,38656)
#define SMEM_BYTES 38656

__global__ void nsc_prepack(const float* __restrict__ W1, const float* __restrict__ W2,
                            const float* __restrict__ W3,
                            bf16* __restrict__ W1p, bf16* __restrict__ W2p,
                            bf16* __restrict__ W3p) {
    int t = blockIdx.x * 256 + threadIdx.x;
    if (t < W1P_ELEMS) {
        int j = t & 7, l = (t >> 3) & 63, t1 = t >> 9;
        int k = (l >> 4) * 8 + j;                      // identity; valid k < 7
        int n = t1 * 16 + (l & 15);
        W1p[t] = (k < 7) ? (bf16)W1[k * HID + n] : (bf16)0.f;
    } else if (t < W1P_ELEMS + W2P_ELEMS) {
        int u = t - W1P_ELEMS;
        int j = u & 7, l = (u >> 3) & 63, ks = (u >> 9) & 3, t2 = u >> 11;
        int p = ks * 32 + (l >> 4) * 8 + j;
        int k = ((p & 7) << 4) | (p >> 3);             // colmap permutation
        int n = t2 * 16 + (l & 15);
        W2p[u] = (bf16)W2[k * HID + n];
    } else if (t < W1P_ELEMS + W2P_ELEMS + W3P_ELEMS) {
        int u = t - W1P_ELEMS - W2P_ELEMS;
        int j = u & 7, l = (u >> 3) & 63, ks = (u >> 9) & 3, t3 = u >> 11;
        int p = ks * 32 + (l >> 4) * 8 + j;
        int k = ((p & 7) << 4) | (p >> 3);             // colmap permutation
        int col = t3 * 16 + (l & 15);
        W3p[u] = (col < OUTD) ? (bf16)W3[k * OUTD + col] : (bf16)0.f;
    }
}

__global__ __launch_bounds__(NT) void nsc_main(
    const float* __restrict__ x, const float* __restrict__ c,
    const bf16* __restrict__ W1p, const float* __restrict__ b1,
    const bf16* __restrict__ W2p, const float* __restrict__ b2,
    const bf16* __restrict__ W3p, const float* __restrict__ b3,
    float* __restrict__ out_y, float* __restrict__ out_ld, int N)
{
    __shared__ __align__(16) char smem[SMEM_BYTES];
    bf16*  shIn = (bf16*)smem;                  // [s][INS]
    bf16*  hbuf = (bf16*)(smem + 5120);         // [s][HS], k-permuted positions
    float* shp  = (float*)smem;                 // [s][3][PRS] (+4 pad), aliases above
    float* shld = (float*)(smem + 37888);       // [s][3]

    const int tid  = threadIdx.x;
    const int g0   = blockIdx.x * TILE;
    const int lane = tid & 63;
    const int wv   = tid >> 6;        // wave id; owns samples wv*16 .. wv*16+15
    const int lm   = lane & 15;
    const int lq   = lane >> 4;
    const int arow = wv * 16 + lm;    // A-fragment row (sample) for this lane

    // ---- Phase 0: stage inputs bf16, identity k positions, zero-padded (wave-private) ----
    if (lane < 16) {
        int s = wv * 16 + lane;
        int g = g0 + s;
        float v[7];
        if (g < N) {
            v[0] = x[g * 6 + 3]; v[1] = x[g * 6 + 4]; v[2] = x[g * 6 + 5];
            v[3] = c[g * 4];     v[4] = c[g * 4 + 1];
            v[5] = c[g * 4 + 2]; v[6] = c[g * 4 + 3];
        } else {
            #pragma unroll
            for (int k = 0; k < 7; ++k) v[k] = 0.f;
        }
        bf16x8 r0 = (bf16x8){(bf16)v[0], (bf16)v[1], (bf16)v[2], (bf16)v[3],
                             (bf16)v[4], (bf16)v[5], (bf16)v[6], (bf16)0.f};
        bf16x8 z  = (bf16x8){(bf16)0.f, (bf16)0.f, (bf16)0.f, (bf16)0.f,
                             (bf16)0.f, (bf16)0.f, (bf16)0.f, (bf16)0.f};
        *(bf16x8*)&shIn[s * INS]      = r0;
        *(bf16x8*)&shIn[s * INS + 8]  = z;
        *(bf16x8*)&shIn[s * INS + 16] = z;
        *(bf16x8*)&shIn[s * INS + 24] = z;
    }
    // no barrier: wave reads only its own rows; DS ops are in-order per wave

    // ---- Phase 1: h1 = relu([h,0] @ W1 + b1) via MFMA (identity k) ----
    {
        f32x4 acc1[8];
        #pragma unroll
        for (int t = 0; t < 8; ++t) {
            float b = b1[t * 16 + lm];
            acc1[t] = (f32x4){b, b, b, b};
        }
        bf16x8 a = *(const bf16x8*)&shIn[arow * INS + lq * 8];
        #pragma unroll
        for (int t = 0; t < 8; ++t) {
            bf16x8 bf = *(const bf16x8*)&W1p[(size_t)(t * 64 + lane) * 8];
            acc1[t] = __builtin_amdgcn_mfma_f32_16x16x32_bf16(a, bf, acc1[t], 0, 0, 0);
        }
        // epilogue: position p = lm*8+t holds col t*16+lm -> one b128 per r
        #pragma unroll
        for (int r = 0; r < 4; ++r) {
            bf16x8 pk;
            #pragma unroll
            for (int t = 0; t < 8; ++t) pk[t] = (bf16)fmaxf(acc1[t][r], 0.f);
            int s = wv * 16 + lq * 4 + r;
            *(bf16x8*)&hbuf[s * HS + lm * 8] = pk;
        }
    }

    // ---- Phase 2: h2 = relu(h1 @ W2 + b2) via MFMA (colmap k); in-place ----
    {
        f32x4 acc2[8];
        #pragma unroll
        for (int t = 0; t < 8; ++t) {
            float b = b2[t * 16 + lm];
            acc2[t] = (f32x4){b, b, b, b};
        }
        #pragma unroll
        for (int ks = 0; ks < 4; ++ks) {
            bf16x8 a = *(const bf16x8*)&hbuf[arow * HS + ks * 32 + lq * 8];
            #pragma unroll
            for (int t = 0; t < 8; ++t) {
                bf16x8 bf = *(const bf16x8*)&W2p[(size_t)((t * 4 + ks) * 64 + lane) * 8];
                acc2[t] = __builtin_amdgcn_mfma_f32_16x16x32_bf16(a, bf, acc2[t], 0, 0, 0);
            }
        }
        #pragma unroll
        for (int r = 0; r < 4; ++r) {
            bf16x8 pk;
            #pragma unroll
            for (int t = 0; t < 8; ++t) pk[t] = (bf16)fmaxf(acc2[t][r], 0.f);
            int s = wv * 16 + lq * 4 + r;
            *(bf16x8*)&hbuf[s * HS + lm * 8] = pk;
        }
    }

    // ---- Phase 3: p = h2 @ W3 + b3 via MFMA (colmap k) ----
    f32x4 acc3[9];
    {
        #pragma unroll
        for (int t = 0; t < 9; ++t) {
            int col = t * 16 + lm;
            float b = (col < OUTD) ? b3[col] : 0.f;
            acc3[t] = (f32x4){b, b, b, b};
        }
        #pragma unroll
        for (int ks = 0; ks < 4; ++ks) {
            bf16x8 a = *(const bf16x8*)&hbuf[arow * HS + ks * 32 + lq * 8];
            #pragma unroll
            for (int t = 0; t < 9; ++t) {
                bf16x8 bf = *(const bf16x8*)&W3p[(size_t)((t * 4 + ks) * 64 + lane) * 8];
                acc3[t] = __builtin_amdgcn_mfma_f32_16x16x32_bf16(a, bf, acc3[t], 0, 0, 0);
            }
        }
    }
    __syncthreads();   // all waves done reading shIn/hbuf -> shp may overwrite

    // epilogue: scatter p into [s][d][48] layout (n-dim unaffected by k-permute)
    #pragma unroll
    for (int t = 0; t < 9; ++t) {
        int col = t * 16 + lm;
        if (col < OUTD) {
            int d = (col >= 94) ? 2 : ((col >= 47) ? 1 : 0);
            int i = col - d * 47;
            #pragma unroll
            for (int r = 0; r < 4; ++r) {
                int s = wv * 16 + lq * 4 + r;
                shp[s * SRS + d * PRS + i] = acc3[t][r];
            }
        }
    }
    __syncthreads();

    // ---- Phase 4: per (sample, dim): softmax -> cumsum -> bin scan -> RQS ----
    if (tid < TILE * 3) {
        const int s = tid / 3, d = tid - s * 3;
        const int g = g0 + s;
        if (g < N) {
            const float* pr = &shp[s * SRS + d * PRS];
            float wv_[16], hv[16], dl[16];
            #pragma unroll
            for (int q = 0; q < 4; ++q) {
                f32x4 v = *(const f32x4*)&pr[q * 4];
                wv_[q*4] = v[0]; wv_[q*4+1] = v[1]; wv_[q*4+2] = v[2]; wv_[q*4+3] = v[3];
            }
            #pragma unroll
            for (int q = 0; q < 4; ++q) {
                f32x4 v = *(const f32x4*)&pr[16 + q * 4];
                hv[q*4] = v[0]; hv[q*4+1] = v[1]; hv[q*4+2] = v[2]; hv[q*4+3] = v[3];
            }
            #pragma unroll
            for (int q = 0; q < 4; ++q) {
                f32x4 v = *(const f32x4*)&pr[32 + q * 4];
                dl[q*4] = v[0]; dl[q*4+1] = v[1]; dl[q*4+2] = v[2]; dl[q*4+3] = v[3];
            }
            // softmax without max-subtract: logits are O(1)
            float sw = 0.f, sh = 0.f;
            #pragma unroll
            for (int i = 0; i < 16; ++i) { wv_[i] = __expf(wv_[i]); sw += wv_[i]; }
            #pragma unroll
            for (int i = 0; i < 16; ++i) { hv[i]  = __expf(hv[i]);  sh += hv[i]; }
            float cwn = 10.f * __builtin_amdgcn_rcpf(sw);
            float chn = 10.f * __builtin_amdgcn_rcpf(sh);
            #pragma unroll
            for (int i = 0; i < 16; ++i) { wv_[i] *= cwn; hv[i] *= chn; }

            float xv = x[g * 6 + d];
            bool oob = (xv <= -BND) || (xv >= BND);
            float xm = oob ? -BND : xv;

            // bin scan; select raw deriv logits (softplus deferred to 2 calls)
            float cumx = -BND + wv_[0], cumy = -BND + hv[0];
            float xk_b = -BND, yk_b = -BND;
            float wk = wv_[0], hk = hv[0];
            float d0l = T1, d1l = dl[0];
            #pragma unroll
            for (int i = 1; i < 16; ++i) {
                bool ge = (xm >= cumx);
                if (ge) {
                    xk_b = cumx; yk_b = cumy;
                    wk = wv_[i]; hk = hv[i];
                    d0l = dl[i - 1];
                    d1l = (i < 15) ? dl[i] : T1;
                }
                cumx += wv_[i]; cumy += hv[i];
            }
            float d0 = (d0l > 15.f) ? d0l : __logf(1.f + __expf(d0l));
            float d1 = (d1l > 15.f) ? d1l : __logf(1.f + __expf(d1l));

            float rwk = __builtin_amdgcn_rcpf(wk);
            float sk = hk * rwk;
            float relx = (xm - xk_b) * rwk;
            relx = fminf(fmaxf(relx, 0.f), 1.f);
            float r1 = relx * (1.f - relx);
            float den = sk + (d1 + d0 - 2.f * sk) * r1;
            float iden = __builtin_amdgcn_rcpf(den);
            float num = hk * (sk * relx * relx + d0 * r1);
            float y = yk_b + num * iden;
            float omr = 1.f - relx;
            float arg = d1 * relx * relx + 2.f * sk * r1 + d0 * omr * omr;
            float ratio = sk * iden;
            float ld = __logf(ratio * ratio * arg);   // 2log(sk)+log(arg)-2log(den)
            if (oob) { y = xv; ld = 0.f; }

            out_y[g * 6 + d] = y;
            out_y[g * 6 + 3 + d] = x[g * 6 + 3 + d];   // upper pass-through (exact fp32)
            shld[s * 3 + d] = ld;
        } else {
            shld[s * 3 + d] = 0.f;
        }
    }
    __syncthreads();

    // ---- Phase 5: reduce log-det over the 3 dims ----
    if (tid < TILE) {
        int g = g0 + tid;
        if (g < N)
            out_ld[g] = shld[tid * 3] + shld[tid * 3 + 1] + shld[tid * 3 + 2];
    }
}

extern "C" void kernel_launch(void* const* d_in, const int* in_sizes, int n_in,
                              void* d_out, int out_size, void* d_ws, size_t ws_size,
                              hipStream_t stream) {
    const float* x  = (const float*)d_in[0];
    const float* c  = (const float*)d_in[1];
    const float* W1 = (const float*)d_in[2];
    const float* b1 = (const float*)d_in[3];
    const float* W2 = (const float*)d_in[4];
    const float* b2 = (const float*)d_in[5];
    const float* W3 = (const float*)d_in[6];
    const float* b3 = (const float*)d_in[7];

    const int N = in_sizes[0] / 6;              // 500000
    float* out_y  = (float*)d_out;
    float* out_ld = (float*)d_out + (size_t)N * 6;

    bf16* W1p = (bf16*)d_ws;
    bf16* W2p = W1p + W1P_ELEMS;
    bf16* W3p = W2p + W2P_ELEMS;

    int total = W1P_ELEMS + W2P_ELEMS + W3P_ELEMS;
    nsc_prepack<<<(total + 255) / 256, 256, 0, stream>>>(W1, W2, W3, W1p, W2p, W3p);

    int nblocks = (N + TILE - 1) / TILE;        // 7813
    nsc_main<<<nblocks, NT, 0, stream>>>(x, c, W1p, b1, W2p, b2, W3p, b3,
                                         out_y, out_ld, N);
}

// Round 6
// 165.507 us; speedup vs baseline: 12.1494x; 1.1086x over previous
//
#include <hip/hip_runtime.h>
#include <math.h>

// NeuralSplineCoupling: y[:, :3] = RQS(x[:, :3]; params = MLP([x[:,3:], c]))
//                       y[:, 3:] = x[:, 3:],  log_det = sum over 3 dims
// N = 500000, X_DIM=6, C_DIM=4, HID=128, KNOTS=16, SPLINE_DIM=47, OUT_DIM=141
//
// Round 6: latency attack. __launch_bounds__(256,4) (LDS caps us at 4 blocks/CU
// anyway) unlocks 128 VGPRs; explicit double-buffered B-fragment prefetch keeps
// ~16 global dwordx4 loads in flight instead of the ~6 the old 68-VGPR budget
// allowed (76 L2-latency-bound loads/wave was the dominant stall). Prepack:
// one thread per fragment (8 elems, single 16B store).

#define TILE 64
#define NT   256
#define HID  128
#define OUTD 141
#define INS  40      // shIn row stride (bf16)
#define HS   136     // h row stride (bf16): 272 B rows, 2-way banks (free)
#define PRS  48      // floats per (sample,dim) p row
#define SRS  148     // floats per sample in shp (tail pad -> bank rotate 20)
#define BND  5.0f
#define T1   0.5413248546f   // ln(e-1): softplus(T1) = 1

typedef __bf16 bf16;
typedef __attribute__((ext_vector_type(8))) __bf16 bf16x8;
typedef __attribute__((ext_vector_type(4))) float f32x4;

#define W1P_ELEMS (8 * 64 * 8)        // identity k-map (features 0..6, rest zero)
#define W2P_ELEMS (8 * 4 * 64 * 8)    // colmap k-permuted
#define W3P_ELEMS (9 * 4 * 64 * 8)    // colmap k-permuted, 144 cols padded

// LDS: [0,5120) shIn | [5120,22528) hbuf ; shp [0,37888) aliases both
// (barrier-separated) | shld [37888,38656)
#define SMEM_BYTES 38656

// One thread per 8-element fragment. Frag f: lane=f&63, tile/ks from f>>6.
// k-permutation for W2/W3: position p -> k = (p&7)*16 + (p>>3)  (colmap).
__global__ void nsc_prepack(const float* __restrict__ W1, const float* __restrict__ W2,
                            const float* __restrict__ W3,
                            bf16* __restrict__ W1p, bf16* __restrict__ W2p,
                            bf16* __restrict__ W3p) {
    int f = blockIdx.x * 256 + threadIdx.x;
    int lane = f & 63, lm = lane & 15, lq = lane >> 4;
    if (f < 512) {                                   // W1: 8 tiles, identity k
        int t = f >> 6;
        int n = t * 16 + lm;
        bf16x8 pk;
        #pragma unroll
        for (int j = 0; j < 8; ++j) {
            int k = lq * 8 + j;
            pk[j] = (k < 7) ? (bf16)W1[k * HID + n] : (bf16)0.f;
        }
        *(bf16x8*)&W1p[(size_t)f * 8] = pk;
    } else if (f < 512 + 2048) {                     // W2: 8 tiles x 4 ks
        int g2 = f - 512;
        int tk = g2 >> 6, t = tk >> 2, ks = tk & 3;
        int n = t * 16 + lm;
        bf16x8 pk;
        #pragma unroll
        for (int j = 0; j < 8; ++j) {
            int p = ks * 32 + lq * 8 + j;
            int k = ((p & 7) << 4) | (p >> 3);
            pk[j] = (bf16)W2[k * HID + n];
        }
        *(bf16x8*)&W2p[(size_t)g2 * 8] = pk;
    } else if (f < 512 + 2048 + 2304) {              // W3: 9 tiles x 4 ks
        int g3 = f - 2560;
        int tk = g3 >> 6, t = tk >> 2, ks = tk & 3;
        int col = t * 16 + lm;
        bf16x8 pk;
        #pragma unroll
        for (int j = 0; j < 8; ++j) {
            int p = ks * 32 + lq * 8 + j;
            int k = ((p & 7) << 4) | (p >> 3);
            pk[j] = (col < OUTD) ? (bf16)W3[k * OUTD + col] : (bf16)0.f;
        }
        *(bf16x8*)&W3p[(size_t)g3 * 8] = pk;
    }
}

__global__ __launch_bounds__(NT, 4) void nsc_main(
    const float* __restrict__ x, const float* __restrict__ c,
    const bf16* __restrict__ W1p, const float* __restrict__ b1,
    const bf16* __restrict__ W2p, const float* __restrict__ b2,
    const bf16* __restrict__ W3p, const float* __restrict__ b3,
    float* __restrict__ out_y, float* __restrict__ out_ld, int N)
{
    __shared__ __align__(16) char smem[SMEM_BYTES];
    bf16*  shIn = (bf16*)smem;                  // [s][INS]
    bf16*  hbuf = (bf16*)(smem + 5120);         // [s][HS], k-permuted positions
    float* shp  = (float*)smem;                 // [s][3][PRS] (+pad), aliases above
    float* shld = (float*)(smem + 37888);       // [s][3]

    const int tid  = threadIdx.x;
    const int g0   = blockIdx.x * TILE;
    const int lane = tid & 63;
    const int wv   = tid >> 6;        // wave id; owns samples wv*16 .. wv*16+15
    const int lm   = lane & 15;
    const int lq   = lane >> 4;
    const int arow = wv * 16 + lm;    // A-fragment row (sample) for this lane

    // ---- Phase 0a: issue input global loads (lanes 0-15 of each wave) ----
    float vin[7];
    const bool ldr = (lane < 16);
    {
        int s = wv * 16 + (lane & 15);
        int g = g0 + s;
        if (ldr && g < N) {
            vin[0] = x[g * 6 + 3]; vin[1] = x[g * 6 + 4]; vin[2] = x[g * 6 + 5];
            vin[3] = c[g * 4];     vin[4] = c[g * 4 + 1];
            vin[5] = c[g * 4 + 2]; vin[6] = c[g * 4 + 3];
        } else {
            #pragma unroll
            for (int k = 0; k < 7; ++k) vin[k] = 0.f;
        }
    }

    // ---- issue W1 frags + phase-2 ks0 frags while inputs are in flight ----
    bf16x8 b1f[8];
    #pragma unroll
    for (int t = 0; t < 8; ++t)
        b1f[t] = *(const bf16x8*)&W1p[(size_t)(t * 64 + lane) * 8];
    bf16x8 b2A[8], b2B[8];
    #pragma unroll
    for (int t = 0; t < 8; ++t)
        b2A[t] = *(const bf16x8*)&W2p[(size_t)((t * 4 + 0) * 64 + lane) * 8];

    // ---- Phase 0b: stage inputs to LDS (wave-private rows; no barrier) ----
    if (ldr) {
        int s = wv * 16 + (lane & 15);
        bf16x8 r0 = (bf16x8){(bf16)vin[0], (bf16)vin[1], (bf16)vin[2], (bf16)vin[3],
                             (bf16)vin[4], (bf16)vin[5], (bf16)vin[6], (bf16)0.f};
        bf16x8 z  = (bf16x8){(bf16)0.f, (bf16)0.f, (bf16)0.f, (bf16)0.f,
                             (bf16)0.f, (bf16)0.f, (bf16)0.f, (bf16)0.f};
        *(bf16x8*)&shIn[s * INS]      = r0;
        *(bf16x8*)&shIn[s * INS + 8]  = z;
        *(bf16x8*)&shIn[s * INS + 16] = z;
        *(bf16x8*)&shIn[s * INS + 24] = z;
    }

    // ---- Phase 1: h1 = relu([h,0] @ W1 + b1) via MFMA (identity k) ----
    {
        f32x4 acc1[8];
        #pragma unroll
        for (int t = 0; t < 8; ++t) {
            float b = b1[t * 16 + lm];
            acc1[t] = (f32x4){b, b, b, b};
        }
        bf16x8 a = *(const bf16x8*)&shIn[arow * INS + lq * 8];
        #pragma unroll
        for (int t = 0; t < 8; ++t)
            acc1[t] = __builtin_amdgcn_mfma_f32_16x16x32_bf16(a, b1f[t], acc1[t], 0, 0, 0);
        // epilogue: position p = lm*8+t holds col t*16+lm -> one b128 per r
        #pragma unroll
        for (int r = 0; r < 4; ++r) {
            bf16x8 pk;
            #pragma unroll
            for (int t = 0; t < 8; ++t) pk[t] = (bf16)fmaxf(acc1[t][r], 0.f);
            int s = wv * 16 + lq * 4 + r;
            *(bf16x8*)&hbuf[s * HS + lm * 8] = pk;
        }
    }

    // ---- Phase 2: h2 = relu(h1 @ W2 + b2); double-buffered B prefetch ----
    {
        f32x4 acc2[8];
        #pragma unroll
        for (int t = 0; t < 8; ++t) {
            float b = b2[t * 16 + lm];
            acc2[t] = (f32x4){b, b, b, b};
        }
        #pragma unroll
        for (int ks = 0; ks < 4; ++ks) {
            bf16x8* cur = (ks & 1) ? b2B : b2A;
            bf16x8* nxt = (ks & 1) ? b2A : b2B;
            if (ks < 3) {
                #pragma unroll
                for (int t = 0; t < 8; ++t)
                    nxt[t] = *(const bf16x8*)&W2p[(size_t)((t * 4 + ks + 1) * 64 + lane) * 8];
            }
            bf16x8 a = *(const bf16x8*)&hbuf[arow * HS + ks * 32 + lq * 8];
            #pragma unroll
            for (int t = 0; t < 8; ++t)
                acc2[t] = __builtin_amdgcn_mfma_f32_16x16x32_bf16(a, cur[t], acc2[t], 0, 0, 0);
        }
        // prefetch phase-3 ks0 B-frags before the epilogue
        #pragma unroll
        for (int t = 0; t < 8; ++t)
            b2A[t] = *(const bf16x8*)&W3p[(size_t)((t * 4 + 0) * 64 + lane) * 8];
        #pragma unroll
        for (int r = 0; r < 4; ++r) {
            bf16x8 pk;
            #pragma unroll
            for (int t = 0; t < 8; ++t) pk[t] = (bf16)fmaxf(acc2[t][r], 0.f);
            int s = wv * 16 + lq * 4 + r;
            *(bf16x8*)&hbuf[s * HS + lm * 8] = pk;
        }
    }

    // ---- Phase 3: p = h2 @ W3 + b3; double-buffered B prefetch (9 tiles) ----
    f32x4 acc3[9];
    {
        #pragma unroll
        for (int t = 0; t < 9; ++t) {
            int col = t * 16 + lm;
            float b = (col < OUTD) ? b3[col] : 0.f;
            acc3[t] = (f32x4){b, b, b, b};
        }
        bf16x8 b3A[9], b3B[9];
        #pragma unroll
        for (int t = 0; t < 8; ++t) b3A[t] = b2A[t];         // already in flight
        b3A[8] = *(const bf16x8*)&W3p[(size_t)((8 * 4 + 0) * 64 + lane) * 8];
        #pragma unroll
        for (int ks = 0; ks < 4; ++ks) {
            bf16x8* cur = (ks & 1) ? b3B : b3A;
            bf16x8* nxt = (ks & 1) ? b3A : b3B;
            if (ks < 3) {
                #pragma unroll
                for (int t = 0; t < 9; ++t)
                    nxt[t] = *(const bf16x8*)&W3p[(size_t)((t * 4 + ks + 1) * 64 + lane) * 8];
            }
            bf16x8 a = *(const bf16x8*)&hbuf[arow * HS + ks * 32 + lq * 8];
            #pragma unroll
            for (int t = 0; t < 9; ++t)
                acc3[t] = __builtin_amdgcn_mfma_f32_16x16x32_bf16(a, cur[t], acc3[t], 0, 0, 0);
        }
    }
    __syncthreads();   // all waves done reading shIn/hbuf -> shp may overwrite

    // epilogue: scatter p into [s][d][48] layout
    #pragma unroll
    for (int t = 0; t < 9; ++t) {
        int col = t * 16 + lm;
        if (col < OUTD) {
            int d = (col >= 94) ? 2 : ((col >= 47) ? 1 : 0);
            int i = col - d * 47;
            #pragma unroll
            for (int r = 0; r < 4; ++r) {
                int s = wv * 16 + lq * 4 + r;
                shp[s * SRS + d * PRS + i] = acc3[t][r];
            }
        }
    }
    __syncthreads();

    // ---- Phase 4: per (sample, dim): softmax -> cumsum -> bin scan -> RQS ----
    if (tid < TILE * 3) {
        const int s = tid / 3, d = tid - s * 3;
        const int g = g0 + s;
        if (g < N) {
            const float* pr = &shp[s * SRS + d * PRS];
            float wv_[16], hv[16], dl[16];
            #pragma unroll
            for (int q = 0; q < 4; ++q) {
                f32x4 v = *(const f32x4*)&pr[q * 4];
                wv_[q*4] = v[0]; wv_[q*4+1] = v[1]; wv_[q*4+2] = v[2]; wv_[q*4+3] = v[3];
            }
            #pragma unroll
            for (int q = 0; q < 4; ++q) {
                f32x4 v = *(const f32x4*)&pr[16 + q * 4];
                hv[q*4] = v[0]; hv[q*4+1] = v[1]; hv[q*4+2] = v[2]; hv[q*4+3] = v[3];
            }
            #pragma unroll
            for (int q = 0; q < 4; ++q) {
                f32x4 v = *(const f32x4*)&pr[32 + q * 4];
                dl[q*4] = v[0]; dl[q*4+1] = v[1]; dl[q*4+2] = v[2]; dl[q*4+3] = v[3];
            }
            // softmax without max-subtract: logits are O(1)
            float sw = 0.f, sh = 0.f;
            #pragma unroll
            for (int i = 0; i < 16; ++i) { wv_[i] = __expf(wv_[i]); sw += wv_[i]; }
            #pragma unroll
            for (int i = 0; i < 16; ++i) { hv[i]  = __expf(hv[i]);  sh += hv[i]; }
            float cwn = 10.f * __builtin_amdgcn_rcpf(sw);
            float chn = 10.f * __builtin_amdgcn_rcpf(sh);
            #pragma unroll
            for (int i = 0; i < 16; ++i) { wv_[i] *= cwn; hv[i] *= chn; }

            float xv = x[g * 6 + d];
            bool oob = (xv <= -BND) || (xv >= BND);
            float xm = oob ? -BND : xv;

            // bin scan; select raw deriv logits (softplus deferred to 2 calls)
            float cumx = -BND + wv_[0], cumy = -BND + hv[0];
            float xk_b = -BND, yk_b = -BND;
            float wk = wv_[0], hk = hv[0];
            float d0l = T1, d1l = dl[0];
            #pragma unroll
            for (int i = 1; i < 16; ++i) {
                bool ge = (xm >= cumx);
                if (ge) {
                    xk_b = cumx; yk_b = cumy;
                    wk = wv_[i]; hk = hv[i];
                    d0l = dl[i - 1];
                    d1l = (i < 15) ? dl[i] : T1;
                }
                cumx += wv_[i]; cumy += hv[i];
            }
            float d0 = (d0l > 15.f) ? d0l : __logf(1.f + __expf(d0l));
            float d1 = (d1l > 15.f) ? d1l : __logf(1.f + __expf(d1l));

            float rwk = __builtin_amdgcn_rcpf(wk);
            float sk = hk * rwk;
            float relx = (xm - xk_b) * rwk;
            relx = fminf(fmaxf(relx, 0.f), 1.f);
            float r1 = relx * (1.f - relx);
            float den = sk + (d1 + d0 - 2.f * sk) * r1;
            float iden = __builtin_amdgcn_rcpf(den);
            float num = hk * (sk * relx * relx + d0 * r1);
            float y = yk_b + num * iden;
            float omr = 1.f - relx;
            float arg = d1 * relx * relx + 2.f * sk * r1 + d0 * omr * omr;
            float ratio = sk * iden;
            float ld = __logf(ratio * ratio * arg);   // 2log(sk)+log(arg)-2log(den)
            if (oob) { y = xv; ld = 0.f; }

            out_y[g * 6 + d] = y;
            out_y[g * 6 + 3 + d] = x[g * 6 + 3 + d];   // upper pass-through (exact fp32)
            shld[s * 3 + d] = ld;
        } else {
            shld[s * 3 + d] = 0.f;
        }
    }
    __syncthreads();

    // ---- Phase 5: reduce log-det over the 3 dims ----
    if (tid < TILE) {
        int g = g0 + tid;
        if (g < N)
            out_ld[g] = shld[tid * 3] + shld[tid * 3 + 1] + shld[tid * 3 + 2];
    }
}

extern "C" void kernel_launch(void* const* d_in, const int* in_sizes, int n_in,
                              void* d_out, int out_size, void* d_ws, size_t ws_size,
                              hipStream_t stream) {
    const float* x  = (const float*)d_in[0];
    const float* c  = (const float*)d_in[1];
    const float* W1 = (const float*)d_in[2];
    const float* b1 = (const float*)d_in[3];
    const float* W2 = (const float*)d_in[4];
    const float* b2 = (const float*)d_in[5];
    const float* W3 = (const float*)d_in[6];
    const float* b3 = (const float*)d_in[7];

    const int N = in_sizes[0] / 6;              // 500000
    float* out_y  = (float*)d_out;
    float* out_ld = (float*)d_out + (size_t)N * 6;

    bf16* W1p = (bf16*)d_ws;
    bf16* W2p = W1p + W1P_ELEMS;
    bf16* W3p = W2p + W2P_ELEMS;

    int nfrag = 512 + 2048 + 2304;              // 4864 fragments
    nsc_prepack<<<(nfrag + 255) / 256, 256, 0, stream>>>(W1, W2, W3, W1p, W2p, W3p);

    int nblocks = (N + TILE - 1) / TILE;        // 7813
    nsc_main<<<nblocks, NT, 0, stream>>>(x, c, W1p, b1, W2p, b2, W3p, b3,
                                         out_y, out_ld, N);
}

// Round 7
// 159.433 us; speedup vs baseline: 12.6122x; 1.0381x over previous
//
#include <hip/hip_runtime.h>
#include <math.h>

// NeuralSplineCoupling: y[:, :3] = RQS(x[:, :3]; params = MLP([x[:,3:], c]))
//                       y[:, 3:] = x[:, 3:],  log_det = sum over 3 dims
// N = 500000, X_DIM=6, C_DIM=4, HID=128, KNOTS=16, SPLINE_DIM=47, OUT_DIM=141
//
// Round 7: TILE=128 with 2 A-rows per wave per B-fragment (wave owns 32
// samples) -> per-sample weight traffic halves, MFMA:B-load 2:1 (was 1:1).
// shp stored fp16 to keep LDS at 46.6 KB -> 3 blocks/CU @ launch_bounds(256,3).
// Spline phase loops 384 (s,d) pairs over 256 threads.

#define TILE 128
#define NT   256
#define HID  128
#define OUTD 141
#define INS  40      // shIn row stride (bf16)
#define HS   136     // hbuf row stride (bf16): 272 B rows, bank-rotate 4
#define PRS  48      // halves per (sample,dim) p row
#define SRS  152     // halves per sample in shp (304 B, 16B-aligned, rotate 12)
#define BND  5.0f
#define T1   0.5413248546f   // ln(e-1): softplus(T1) = 1

typedef __bf16 bf16;
typedef _Float16 f16;
typedef __attribute__((ext_vector_type(8))) __bf16 bf16x8;
typedef __attribute__((ext_vector_type(8))) _Float16 f16x8;
typedef __attribute__((ext_vector_type(4))) float f32x4;

#define W1P_ELEMS (8 * 64 * 8)        // identity k-map (features 0..6, rest zero)
#define W2P_ELEMS (8 * 4 * 64 * 8)    // colmap k-permuted
#define W3P_ELEMS (9 * 4 * 64 * 8)    // colmap k-permuted, 144 cols padded

// LDS (bytes): shIn [0,10240) | hbuf [10240,45056) ; shp fp16 [0,38912)
// aliases both (barrier-separated) | shld [45056,46592)
#define SMEM_BYTES 46592

// One thread per 8-element B fragment; k-permutation colmap(p)=(p&7)*16+(p>>3).
__global__ void nsc_prepack(const float* __restrict__ W1, const float* __restrict__ W2,
                            const float* __restrict__ W3,
                            bf16* __restrict__ W1p, bf16* __restrict__ W2p,
                            bf16* __restrict__ W3p) {
    int f = blockIdx.x * 256 + threadIdx.x;
    int lane = f & 63, lm = lane & 15, lq = lane >> 4;
    if (f < 512) {                                   // W1: 8 tiles, identity k
        int t = f >> 6;
        int n = t * 16 + lm;
        bf16x8 pk;
        #pragma unroll
        for (int j = 0; j < 8; ++j) {
            int k = lq * 8 + j;
            pk[j] = (k < 7) ? (bf16)W1[k * HID + n] : (bf16)0.f;
        }
        *(bf16x8*)&W1p[(size_t)f * 8] = pk;
    } else if (f < 512 + 2048) {                     // W2: 8 tiles x 4 ks
        int g2 = f - 512;
        int tk = g2 >> 6, t = tk >> 2, ks = tk & 3;
        int n = t * 16 + lm;
        bf16x8 pk;
        #pragma unroll
        for (int j = 0; j < 8; ++j) {
            int p = ks * 32 + lq * 8 + j;
            int k = ((p & 7) << 4) | (p >> 3);
            pk[j] = (bf16)W2[k * HID + n];
        }
        *(bf16x8*)&W2p[(size_t)g2 * 8] = pk;
    } else if (f < 512 + 2048 + 2304) {              // W3: 9 tiles x 4 ks
        int g3 = f - 2560;
        int tk = g3 >> 6, t = tk >> 2, ks = tk & 3;
        int col = t * 16 + lm;
        bf16x8 pk;
        #pragma unroll
        for (int j = 0; j < 8; ++j) {
            int p = ks * 32 + lq * 8 + j;
            int k = ((p & 7) << 4) | (p >> 3);
            pk[j] = (col < OUTD) ? (bf16)W3[k * OUTD + col] : (bf16)0.f;
        }
        *(bf16x8*)&W3p[(size_t)g3 * 8] = pk;
    }
}

__global__ __launch_bounds__(NT, 3) void nsc_main(
    const float* __restrict__ x, const float* __restrict__ c,
    const bf16* __restrict__ W1p, const float* __restrict__ b1,
    const bf16* __restrict__ W2p, const float* __restrict__ b2,
    const bf16* __restrict__ W3p, const float* __restrict__ b3,
    float* __restrict__ out_y, float* __restrict__ out_ld, int N)
{
    __shared__ __align__(16) char smem[SMEM_BYTES];
    bf16*  shIn  = (bf16*)smem;                 // [s][INS]
    bf16*  hbuf  = (bf16*)(smem + 10240);       // [s][HS], k-permuted positions
    f16*   shp16 = (f16*)smem;                  // [s][3][PRS] fp16, aliases above
    float* shld  = (float*)(smem + 45056);      // [s][3]

    const int tid  = threadIdx.x;
    const int g0   = blockIdx.x * TILE;
    const int lane = tid & 63;
    const int wv   = tid >> 6;        // wave id; owns samples wv*32 .. wv*32+31
    const int lm   = lane & 15;
    const int lq   = lane >> 4;
    const int sbase = wv * 32;
    const int arow0 = sbase + lm;     // A-row for arow block 0
    const int arow1 = sbase + 16 + lm;

    // ---- Phase 0: stage inputs bf16 (lanes 0-31, wave-private rows) ----
    if (lane < 32) {
        int s = sbase + lane;
        int g = g0 + s;
        float v[7];
        if (g < N) {
            v[0] = x[g * 6 + 3]; v[1] = x[g * 6 + 4]; v[2] = x[g * 6 + 5];
            v[3] = c[g * 4];     v[4] = c[g * 4 + 1];
            v[5] = c[g * 4 + 2]; v[6] = c[g * 4 + 3];
        } else {
            #pragma unroll
            for (int k = 0; k < 7; ++k) v[k] = 0.f;
        }
        bf16x8 r0 = (bf16x8){(bf16)v[0], (bf16)v[1], (bf16)v[2], (bf16)v[3],
                             (bf16)v[4], (bf16)v[5], (bf16)v[6], (bf16)0.f};
        bf16x8 z  = (bf16x8){(bf16)0.f, (bf16)0.f, (bf16)0.f, (bf16)0.f,
                             (bf16)0.f, (bf16)0.f, (bf16)0.f, (bf16)0.f};
        *(bf16x8*)&shIn[s * INS]      = r0;
        *(bf16x8*)&shIn[s * INS + 8]  = z;
        *(bf16x8*)&shIn[s * INS + 16] = z;
        *(bf16x8*)&shIn[s * INS + 24] = z;
    }
    // no barrier: each wave reads only its own rows; DS is in-order per wave

    // ---- Phase 1: h1 = relu([h,0] @ W1 + b1); 2 A-rows per B-frag ----
    {
        f32x4 acc1[2][8];
        #pragma unroll
        for (int t = 0; t < 8; ++t) {
            float b = b1[t * 16 + lm];
            acc1[0][t] = (f32x4){b, b, b, b};
            acc1[1][t] = (f32x4){b, b, b, b};
        }
        bf16x8 a0 = *(const bf16x8*)&shIn[arow0 * INS + lq * 8];
        bf16x8 a1 = *(const bf16x8*)&shIn[arow1 * INS + lq * 8];
        #pragma unroll
        for (int t = 0; t < 8; ++t) {
            bf16x8 bf = *(const bf16x8*)&W1p[(size_t)(t * 64 + lane) * 8];
            acc1[0][t] = __builtin_amdgcn_mfma_f32_16x16x32_bf16(a0, bf, acc1[0][t], 0, 0, 0);
            acc1[1][t] = __builtin_amdgcn_mfma_f32_16x16x32_bf16(a1, bf, acc1[1][t], 0, 0, 0);
        }
        // epilogue: position p = lm*8+t holds col t*16+lm -> one b128 per (ar,r)
        #pragma unroll
        for (int ar = 0; ar < 2; ++ar)
            #pragma unroll
            for (int r = 0; r < 4; ++r) {
                bf16x8 pk;
                #pragma unroll
                for (int t = 0; t < 8; ++t) pk[t] = (bf16)fmaxf(acc1[ar][t][r], 0.f);
                int s = sbase + ar * 16 + lq * 4 + r;
                *(bf16x8*)&hbuf[s * HS + lm * 8] = pk;
            }
    }

    // ---- Phase 2: h2 = relu(h1 @ W2 + b2); in-place overwrite ----
    {
        f32x4 acc2[2][8];
        #pragma unroll
        for (int t = 0; t < 8; ++t) {
            float b = b2[t * 16 + lm];
            acc2[0][t] = (f32x4){b, b, b, b};
            acc2[1][t] = (f32x4){b, b, b, b};
        }
        #pragma unroll
        for (int ks = 0; ks < 4; ++ks) {
            bf16x8 a0 = *(const bf16x8*)&hbuf[arow0 * HS + ks * 32 + lq * 8];
            bf16x8 a1 = *(const bf16x8*)&hbuf[arow1 * HS + ks * 32 + lq * 8];
            #pragma unroll
            for (int t = 0; t < 8; ++t) {
                bf16x8 bf = *(const bf16x8*)&W2p[(size_t)((t * 4 + ks) * 64 + lane) * 8];
                acc2[0][t] = __builtin_amdgcn_mfma_f32_16x16x32_bf16(a0, bf, acc2[0][t], 0, 0, 0);
                acc2[1][t] = __builtin_amdgcn_mfma_f32_16x16x32_bf16(a1, bf, acc2[1][t], 0, 0, 0);
            }
        }
        #pragma unroll
        for (int ar = 0; ar < 2; ++ar)
            #pragma unroll
            for (int r = 0; r < 4; ++r) {
                bf16x8 pk;
                #pragma unroll
                for (int t = 0; t < 8; ++t) pk[t] = (bf16)fmaxf(acc2[ar][t][r], 0.f);
                int s = sbase + ar * 16 + lq * 4 + r;
                *(bf16x8*)&hbuf[s * HS + lm * 8] = pk;
            }
    }

    // ---- Phase 3: p = h2 @ W3 + b3 (9 tiles, 144 cols) ----
    f32x4 acc3[2][9];
    {
        #pragma unroll
        for (int t = 0; t < 9; ++t) {
            int col = t * 16 + lm;
            float b = (col < OUTD) ? b3[col] : 0.f;
            acc3[0][t] = (f32x4){b, b, b, b};
            acc3[1][t] = (f32x4){b, b, b, b};
        }
        #pragma unroll
        for (int ks = 0; ks < 4; ++ks) {
            bf16x8 a0 = *(const bf16x8*)&hbuf[arow0 * HS + ks * 32 + lq * 8];
            bf16x8 a1 = *(const bf16x8*)&hbuf[arow1 * HS + ks * 32 + lq * 8];
            #pragma unroll
            for (int t = 0; t < 9; ++t) {
                bf16x8 bf = *(const bf16x8*)&W3p[(size_t)((t * 4 + ks) * 64 + lane) * 8];
                acc3[0][t] = __builtin_amdgcn_mfma_f32_16x16x32_bf16(a0, bf, acc3[0][t], 0, 0, 0);
                acc3[1][t] = __builtin_amdgcn_mfma_f32_16x16x32_bf16(a1, bf, acc3[1][t], 0, 0, 0);
            }
        }
    }
    __syncthreads();   // all waves done reading shIn/hbuf -> shp may overwrite

    // epilogue: scatter p (fp16) into [s][d][48]
    #pragma unroll
    for (int t = 0; t < 9; ++t) {
        int col = t * 16 + lm;
        if (col < OUTD) {
            int d = (col >= 94) ? 2 : ((col >= 47) ? 1 : 0);
            int i = col - d * 47;
            #pragma unroll
            for (int ar = 0; ar < 2; ++ar)
                #pragma unroll
                for (int r = 0; r < 4; ++r) {
                    int s = sbase + ar * 16 + lq * 4 + r;
                    shp16[s * SRS + d * PRS + i] = (f16)acc3[ar][t][r];
                }
        }
    }
    __syncthreads();

    // ---- Phase 4: per (sample, dim): softmax -> bin scan -> RQS ----
    for (int pidx = tid; pidx < TILE * 3; pidx += NT) {
        const int s = pidx / 3, d = pidx - s * 3;
        const int g = g0 + s;
        if (g < N) {
            const f16* pr = &shp16[s * SRS + d * PRS];
            f16x8 v0 = *(const f16x8*)&pr[0];
            f16x8 v1 = *(const f16x8*)&pr[8];
            f16x8 v2 = *(const f16x8*)&pr[16];
            f16x8 v3 = *(const f16x8*)&pr[24];
            f16x8 v4 = *(const f16x8*)&pr[32];
            f16x8 v5 = *(const f16x8*)&pr[40];
            float wv_[16], hv[16], dl[15];
            #pragma unroll
            for (int i = 0; i < 8; ++i) {
                wv_[i] = (float)v0[i]; wv_[8 + i] = (float)v1[i];
                hv[i]  = (float)v2[i]; hv[8 + i]  = (float)v3[i];
            }
            #pragma unroll
            for (int i = 0; i < 8; ++i) dl[i] = (float)v4[i];
            #pragma unroll
            for (int i = 0; i < 7; ++i) dl[8 + i] = (float)v5[i];   // v5[7] = pad

            // softmax without max-subtract: logits are O(1)
            float sw = 0.f, sh = 0.f;
            #pragma unroll
            for (int i = 0; i < 16; ++i) { wv_[i] = __expf(wv_[i]); sw += wv_[i]; }
            #pragma unroll
            for (int i = 0; i < 16; ++i) { hv[i]  = __expf(hv[i]);  sh += hv[i]; }
            float cwn = 10.f * __builtin_amdgcn_rcpf(sw);
            float chn = 10.f * __builtin_amdgcn_rcpf(sh);
            #pragma unroll
            for (int i = 0; i < 16; ++i) { wv_[i] *= cwn; hv[i] *= chn; }

            float xv = x[g * 6 + d];
            bool oob = (xv <= -BND) || (xv >= BND);
            float xm = oob ? -BND : xv;

            // bin scan; softplus deferred to the 2 selected derivs
            float cumx = -BND + wv_[0], cumy = -BND + hv[0];
            float xk_b = -BND, yk_b = -BND;
            float wk = wv_[0], hk = hv[0];
            float d0l = T1, d1l = dl[0];
            #pragma unroll
            for (int i = 1; i < 16; ++i) {
                bool ge = (xm >= cumx);
                if (ge) {
                    xk_b = cumx; yk_b = cumy;
                    wk = wv_[i]; hk = hv[i];
                    d0l = dl[i - 1];
                    d1l = (i < 15) ? dl[i] : T1;
                }
                cumx += wv_[i]; cumy += hv[i];
            }
            float d0 = (d0l > 15.f) ? d0l : __logf(1.f + __expf(d0l));
            float d1 = (d1l > 15.f) ? d1l : __logf(1.f + __expf(d1l));

            float rwk = __builtin_amdgcn_rcpf(wk);
            float sk = hk * rwk;
            float relx = (xm - xk_b) * rwk;
            relx = fminf(fmaxf(relx, 0.f), 1.f);
            float r1 = relx * (1.f - relx);
            float den = sk + (d1 + d0 - 2.f * sk) * r1;
            float iden = __builtin_amdgcn_rcpf(den);
            float num = hk * (sk * relx * relx + d0 * r1);
            float y = yk_b + num * iden;
            float omr = 1.f - relx;
            float arg = d1 * relx * relx + 2.f * sk * r1 + d0 * omr * omr;
            float ratio = sk * iden;
            float ld = __logf(ratio * ratio * arg);   // 2log(sk)+log(arg)-2log(den)
            if (oob) { y = xv; ld = 0.f; }

            out_y[g * 6 + d] = y;
            out_y[g * 6 + 3 + d] = x[g * 6 + 3 + d];   // upper pass-through (fp32)
            shld[s * 3 + d] = ld;
        }
    }
    __syncthreads();

    // ---- Phase 5: reduce log-det over the 3 dims ----
    if (tid < TILE) {
        int g = g0 + tid;
        if (g < N)
            out_ld[g] = shld[tid * 3] + shld[tid * 3 + 1] + shld[tid * 3 + 2];
    }
}

extern "C" void kernel_launch(void* const* d_in, const int* in_sizes, int n_in,
                              void* d_out, int out_size, void* d_ws, size_t ws_size,
                              hipStream_t stream) {
    const float* x  = (const float*)d_in[0];
    const float* c  = (const float*)d_in[1];
    const float* W1 = (const float*)d_in[2];
    const float* b1 = (const float*)d_in[3];
    const float* W2 = (const float*)d_in[4];
    const float* b2 = (const float*)d_in[5];
    const float* W3 = (const float*)d_in[6];
    const float* b3 = (const float*)d_in[7];

    const int N = in_sizes[0] / 6;              // 500000
    float* out_y  = (float*)d_out;
    float* out_ld = (float*)d_out + (size_t)N * 6;

    bf16* W1p = (bf16*)d_ws;
    bf16* W2p = W1p + W1P_ELEMS;
    bf16* W3p = W2p + W2P_ELEMS;

    int nfrag = 512 + 2048 + 2304;              // 4864 fragments
    nsc_prepack<<<(nfrag + 255) / 256, 256, 0, stream>>>(W1, W2, W3, W1p, W2p, W3p);

    int nblocks = (N + TILE - 1) / TILE;        // 3907
    nsc_main<<<nblocks, NT, 0, stream>>>(x, c, W1p, b1, W2p, b2, W3p, b3,
                                         out_y, out_ld, N);
}